// Round 1
// baseline (647.761 us; speedup 1.0000x reference)
//
#include <hip/hip_runtime.h>
#include <hip/hip_bf16.h>
#include <math.h>

#define B_   8
#define S_   2048
#define IN_  512
#define OUT_ 256
#define G_   8

// ws layout: [0, 16MB) = y (pre-LN then x_t, in-place), [16MB, 20MB) = PT (float2)

__device__ __forceinline__ float cos2pi(float f) {
    // f in [0,1): v_cos_f32 takes revolutions
#if __has_builtin(__builtin_amdgcn_cosf)
    return __builtin_amdgcn_cosf(f);
#else
    return __cosf(6.28318530717958647692f * f);
#endif
}

__global__ void prep_pt(const float* __restrict__ P, const float* __restrict__ periods,
                        float2* __restrict__ PT, int n) {
    int idx = blockIdx.x * 256 + threadIdx.x;
    if (idx < n) PT[idx] = make_float2(P[idx], 1.0f / periods[idx]);
}

// C = x(16384x512) * W^T, 128x128 tiles. col tiles 0,1 -> y (pre-LN), 2,3 -> out (residual)
__global__ __launch_bounds__(256) void gemm_kernel(const float* __restrict__ x,
                                                   const float* __restrict__ M,
                                                   const float* __restrict__ Wres,
                                                   float* __restrict__ y,
                                                   float* __restrict__ out) {
    __shared__ float As[8][132];
    __shared__ float Bs[8][132];
    const int ct = blockIdx.x;      // 0..3
    const int rt = blockIdx.y;      // 0..127
    const int t  = threadIdx.x;
    const int row0 = rt * 128;
    const float* W = (ct < 2) ? M : Wres;
    const int wcol0 = (ct & 1) * 128;

    float acc[8][8];
#pragma unroll
    for (int r = 0; r < 8; ++r)
#pragma unroll
        for (int c = 0; c < 8; ++c) acc[r][c] = 0.0f;

    const int lr = t >> 1;          // 0..127
    const int lk = (t & 1) << 2;    // 0 or 4

    for (int k0 = 0; k0 < 512; k0 += 8) {
        float4 av = *(const float4*)(x + (size_t)(row0 + lr) * 512 + k0 + lk);
        float4 bv = *(const float4*)(W + (size_t)(wcol0 + lr) * 512 + k0 + lk);
        __syncthreads();
        As[lk + 0][lr] = av.x; As[lk + 1][lr] = av.y; As[lk + 2][lr] = av.z; As[lk + 3][lr] = av.w;
        Bs[lk + 0][lr] = bv.x; Bs[lk + 1][lr] = bv.y; Bs[lk + 2][lr] = bv.z; Bs[lk + 3][lr] = bv.w;
        __syncthreads();
        const int tx = t & 15, ty = t >> 4;
#pragma unroll
        for (int kk = 0; kk < 8; ++kk) {
            const float4 a0 = *(const float4*)&As[kk][ty * 8];
            const float4 a1 = *(const float4*)&As[kk][ty * 8 + 4];
            const float4 b0 = *(const float4*)&Bs[kk][tx * 8];
            const float4 b1 = *(const float4*)&Bs[kk][tx * 8 + 4];
            const float ar[8] = {a0.x, a0.y, a0.z, a0.w, a1.x, a1.y, a1.z, a1.w};
            const float br[8] = {b0.x, b0.y, b0.z, b0.w, b1.x, b1.y, b1.z, b1.w};
#pragma unroll
            for (int r = 0; r < 8; ++r)
#pragma unroll
                for (int c = 0; c < 8; ++c) acc[r][c] = fmaf(ar[r], br[c], acc[r][c]);
        }
    }

    const int tx = t & 15, ty = t >> 4;
    float* dst = (ct < 2) ? y : out;
    const int cbase = (ct & 1) * 128 + tx * 8;
#pragma unroll
    for (int r = 0; r < 8; ++r) {
        float4 v0 = {acc[r][0], acc[r][1], acc[r][2], acc[r][3]};
        float4 v1 = {acc[r][4], acc[r][5], acc[r][6], acc[r][7]};
        float* p = dst + (size_t)(row0 + ty * 8 + r) * 256 + cbase;
        *(float4*)(p)     = v0;
        *(float4*)(p + 4) = v1;
    }
}

// In-place LayerNorm over last dim (256) of y. One wave per row.
__global__ __launch_bounds__(256) void ln_kernel(float* __restrict__ y,
                                                 const float* __restrict__ scale,
                                                 const float* __restrict__ bias) {
    const int t    = threadIdx.x;
    const int row  = blockIdx.x * 4 + (t >> 6);
    const int lane = t & 63;
    float* p = y + (size_t)row * 256 + lane * 4;
    float4 v = *(float4*)p;
    float s  = v.x + v.y + v.z + v.w;
    float ss = v.x * v.x + v.y * v.y + v.z * v.z + v.w * v.w;
#pragma unroll
    for (int off = 32; off > 0; off >>= 1) {
        s  += __shfl_xor(s, off);
        ss += __shfl_xor(ss, off);
    }
    const float mu  = s * (1.0f / 256.0f);
    const float var = ss * (1.0f / 256.0f) - mu * mu;
    const float rs  = rsqrtf(var + 1e-5f);
    float4 sc = *(const float4*)(scale + lane * 4);
    float4 bi = *(const float4*)(bias + lane * 4);
    float4 o;
    o.x = (v.x - mu) * rs * sc.x + bi.x;
    o.y = (v.y - mu) * rs * sc.y + bi.y;
    o.z = (v.z - mu) * rs * sc.z + bi.z;
    o.w = (v.w - mu) * rs * sc.w + bi.w;
    *(float4*)p = o;
}

// Fused A-generation + Nk contraction. One WG per 4 consecutive s.
// Thread t: i0 = t&127, i1 = i0+128; st half = (t>>7)*2 .. +1. acc[ih][s2][b].
__global__ __launch_bounds__(256) void cosnk(const float2* __restrict__ PT,
                                             const float* __restrict__ xt,
                                             float* __restrict__ out) {
    __shared__ float xs[256][32];   // [j][st*8+b], 32 KB
    const int t  = threadIdx.x;
    const int s0 = blockIdx.x * 4;

    {   // stage x_t tile: 32 rows (st,b) x 256 j
        const int slot = t >> 3;        // 0..31 == st*8+b
        const int st   = slot >> 3;
        const int b    = slot & 7;
        const int jb   = (t & 7) * 32;
        const float* src = xt + (size_t)(b * S_ + s0 + st) * 256 + jb;
#pragma unroll
        for (int q = 0; q < 8; ++q) {
            float4 v = *(const float4*)(src + 4 * q);
            xs[jb + 4 * q + 0][slot] = v.x;
            xs[jb + 4 * q + 1][slot] = v.y;
            xs[jb + 4 * q + 2][slot] = v.z;
            xs[jb + 4 * q + 3][slot] = v.w;
        }
    }
    __syncthreads();

    const int i0 = t & 127;
    const int i1 = i0 + 128;
    const int sb = (t >> 7) * 2;    // st base: 0 or 2
    const float sv0 = (float)(s0 + sb);
    const float sv1 = (float)(s0 + sb + 1);

    float acc[2][2][8];
#pragma unroll
    for (int ih = 0; ih < 2; ++ih)
#pragma unroll
        for (int s2 = 0; s2 < 2; ++s2)
#pragma unroll
            for (int b = 0; b < 8; ++b) acc[ih][s2][b] = 0.0f;

    const float2* r0 = PT + (size_t)i0 * 2048;  // i*(256*8)
    const float2* r1 = PT + (size_t)i1 * 2048;

    for (int j = 0; j < 256; ++j) {
        const float4* pA = (const float4*)(r0 + j * 8);  // 4 float4 = 8 (p, invT)
        const float4* pB = (const float4*)(r1 + j * 8);
        float a[2][2] = {{0.0f, 0.0f}, {0.0f, 0.0f}};
#pragma unroll
        for (int h = 0; h < 4; ++h) {
            const float4 qa = pA[h];
            const float4 qb = pB[h];
            {
                float f0 = sv0 * qa.y; f0 -= floorf(f0);
                float f1 = sv1 * qa.y; f1 -= floorf(f1);
                a[0][0] = fmaf(qa.x, cos2pi(f0), a[0][0]);
                a[0][1] = fmaf(qa.x, cos2pi(f1), a[0][1]);
            }
            {
                float f0 = sv0 * qa.w; f0 -= floorf(f0);
                float f1 = sv1 * qa.w; f1 -= floorf(f1);
                a[0][0] = fmaf(qa.z, cos2pi(f0), a[0][0]);
                a[0][1] = fmaf(qa.z, cos2pi(f1), a[0][1]);
            }
            {
                float f0 = sv0 * qb.y; f0 -= floorf(f0);
                float f1 = sv1 * qb.y; f1 -= floorf(f1);
                a[1][0] = fmaf(qb.x, cos2pi(f0), a[1][0]);
                a[1][1] = fmaf(qb.x, cos2pi(f1), a[1][1]);
            }
            {
                float f0 = sv0 * qb.w; f0 -= floorf(f0);
                float f1 = sv1 * qb.w; f1 -= floorf(f1);
                a[1][0] = fmaf(qb.z, cos2pi(f0), a[1][0]);
                a[1][1] = fmaf(qb.z, cos2pi(f1), a[1][1]);
            }
        }
        const float* xrow = &xs[j][sb * 8];
#pragma unroll
        for (int s2 = 0; s2 < 2; ++s2) {
            const float4 xa = *(const float4*)(xrow + s2 * 8);
            const float4 xb = *(const float4*)(xrow + s2 * 8 + 4);
            const float xv[8] = {xa.x, xa.y, xa.z, xa.w, xb.x, xb.y, xb.z, xb.w};
#pragma unroll
            for (int b = 0; b < 8; ++b) {
                acc[0][s2][b] = fmaf(a[0][s2], xv[b], acc[0][s2][b]);
                acc[1][s2][b] = fmaf(a[1][s2], xv[b], acc[1][s2][b]);
            }
        }
    }

#pragma unroll
    for (int s2 = 0; s2 < 2; ++s2)
#pragma unroll
        for (int b = 0; b < 8; ++b) {
            const size_t base = (size_t)(b * S_ + s0 + sb + s2) * 256;
            out[base + i0] += acc[0][s2][b];
            out[base + i1] += acc[1][s2][b];
        }
}

extern "C" void kernel_launch(void* const* d_in, const int* in_sizes, int n_in,
                              void* d_out, int out_size, void* d_ws, size_t ws_size,
                              hipStream_t stream) {
    const float* x        = (const float*)d_in[0];
    const float* M        = (const float*)d_in[1];
    const float* P        = (const float*)d_in[2];
    const float* Wres     = (const float*)d_in[3];
    const float* ln_scale = (const float*)d_in[4];
    const float* ln_bias  = (const float*)d_in[5];
    const float* periods  = (const float*)d_in[6];
    // d_in[7] = positions (== arange(S)), used implicitly as s index

    float*  out = (float*)d_out;
    float*  y   = (float*)d_ws;                                    // 16 MB
    float2* PT  = (float2*)((char*)d_ws + (size_t)16 * 1024 * 1024); // 4 MB

    prep_pt<<<2048, 256, 0, stream>>>(P, periods, PT, OUT_ * OUT_ * G_);

    dim3 ggrid(4, 128);
    gemm_kernel<<<ggrid, 256, 0, stream>>>(x, M, Wres, y, out);

    ln_kernel<<<4096, 256, 0, stream>>>(y, ln_scale, ln_bias);

    cosnk<<<512, 256, 0, stream>>>(PT, y, out);
}

// Round 2
// 355.034 us; speedup vs baseline: 1.8245x; 1.8245x over previous
//
#include <hip/hip_runtime.h>
#include <hip/hip_bf16.h>
#include <math.h>

#define B_   8
#define S_   2048
#define IN_  512
#define OUT_ 256
#define G_   8

// ws layout: [0, 16MiB) = y (pre-LN then x_t, in-place; exactly 16 MiB)
//            [16MiB, 22MiB) = PTK float4 table, layout [j][quad][i]:
//              quad 0..3 = (p,invT) pairs for g=2q,2q+1 ; quad 4 = 2k[g0..3], quad 5 = 2k[g4..7]

__device__ __forceinline__ float cos2pi(float f) {
    // f in revolutions; v_cos_f32 takes revolutions (verified R1: passed with this)
#if __has_builtin(__builtin_amdgcn_cosf)
    return __builtin_amdgcn_cosf(f);
#else
    return __cosf(6.28318530717958647692f * f);
#endif
}

__device__ __forceinline__ float fractf_(float f) {
#if __has_builtin(__builtin_amdgcn_fractf)
    return __builtin_amdgcn_fractf(f);
#else
    return f - floorf(f);
#endif
}

// Build i-coalesced table. tid = j*256 + i.
__global__ __launch_bounds__(256) void prep_ptk(const float* __restrict__ P,
                                                const float* __restrict__ periods,
                                                float4* __restrict__ PTK) {
    const int tid = blockIdx.x * 256 + threadIdx.x;
    const int j = tid >> 8, i = tid & 255;
    float p[8], iT[8], k2[8];
#pragma unroll
    for (int g = 0; g < 8; ++g) {
        const int idx = (i * 256 + j) * 8 + g;
        p[g]  = P[idx];
        iT[g] = 1.0f / periods[idx];
        k2[g] = 2.0f * cos2pi(iT[g]);
    }
    float4* base = PTK + (size_t)(j * 6) * 256 + i;
    base[0]    = make_float4(p[0], iT[0], p[1], iT[1]);
    base[256]  = make_float4(p[2], iT[2], p[3], iT[3]);
    base[512]  = make_float4(p[4], iT[4], p[5], iT[5]);
    base[768]  = make_float4(p[6], iT[6], p[7], iT[7]);
    base[1024] = make_float4(k2[0], k2[1], k2[2], k2[3]);
    base[1280] = make_float4(k2[4], k2[5], k2[6], k2[7]);
}

// C = x(16384x512) * W^T, 128x128 tiles. col tiles 0,1 -> y (pre-LN), 2,3 -> out (residual)
__global__ __launch_bounds__(256) void gemm_kernel(const float* __restrict__ x,
                                                   const float* __restrict__ M,
                                                   const float* __restrict__ Wres,
                                                   float* __restrict__ y,
                                                   float* __restrict__ out) {
    __shared__ float As[8][132];
    __shared__ float Bs[8][132];
    const int ct = blockIdx.x;      // 0..3
    const int rt = blockIdx.y;      // 0..127
    const int t  = threadIdx.x;
    const int row0 = rt * 128;
    const float* W = (ct < 2) ? M : Wres;
    const int wcol0 = (ct & 1) * 128;

    float acc[8][8];
#pragma unroll
    for (int r = 0; r < 8; ++r)
#pragma unroll
        for (int c = 0; c < 8; ++c) acc[r][c] = 0.0f;

    const int lr = t >> 1;          // 0..127
    const int lk = (t & 1) << 2;    // 0 or 4

    for (int k0 = 0; k0 < 512; k0 += 8) {
        float4 av = *(const float4*)(x + (size_t)(row0 + lr) * 512 + k0 + lk);
        float4 bv = *(const float4*)(W + (size_t)(wcol0 + lr) * 512 + k0 + lk);
        __syncthreads();
        As[lk + 0][lr] = av.x; As[lk + 1][lr] = av.y; As[lk + 2][lr] = av.z; As[lk + 3][lr] = av.w;
        Bs[lk + 0][lr] = bv.x; Bs[lk + 1][lr] = bv.y; Bs[lk + 2][lr] = bv.z; Bs[lk + 3][lr] = bv.w;
        __syncthreads();
        const int tx = t & 15, ty = t >> 4;
#pragma unroll
        for (int kk = 0; kk < 8; ++kk) {
            const float4 a0 = *(const float4*)&As[kk][ty * 8];
            const float4 a1 = *(const float4*)&As[kk][ty * 8 + 4];
            const float4 b0 = *(const float4*)&Bs[kk][tx * 8];
            const float4 b1 = *(const float4*)&Bs[kk][tx * 8 + 4];
            const float ar[8] = {a0.x, a0.y, a0.z, a0.w, a1.x, a1.y, a1.z, a1.w};
            const float br[8] = {b0.x, b0.y, b0.z, b0.w, b1.x, b1.y, b1.z, b1.w};
#pragma unroll
            for (int r = 0; r < 8; ++r)
#pragma unroll
                for (int c = 0; c < 8; ++c) acc[r][c] = fmaf(ar[r], br[c], acc[r][c]);
        }
    }

    const int tx = t & 15, ty = t >> 4;
    float* dst = (ct < 2) ? y : out;
    const int cbase = (ct & 1) * 128 + tx * 8;
#pragma unroll
    for (int r = 0; r < 8; ++r) {
        float4 v0 = {acc[r][0], acc[r][1], acc[r][2], acc[r][3]};
        float4 v1 = {acc[r][4], acc[r][5], acc[r][6], acc[r][7]};
        float* p = dst + (size_t)(row0 + ty * 8 + r) * 256 + cbase;
        *(float4*)(p)     = v0;
        *(float4*)(p + 4) = v1;
    }
}

// In-place LayerNorm over last dim (256) of y. One wave per row.
__global__ __launch_bounds__(256) void ln_kernel(float* __restrict__ y,
                                                 const float* __restrict__ scale,
                                                 const float* __restrict__ bias) {
    const int t    = threadIdx.x;
    const int row  = blockIdx.x * 4 + (t >> 6);
    const int lane = t & 63;
    float* p = y + (size_t)row * 256 + lane * 4;
    float4 v = *(float4*)p;
    float s  = v.x + v.y + v.z + v.w;
    float ss = v.x * v.x + v.y * v.y + v.z * v.z + v.w * v.w;
#pragma unroll
    for (int off = 32; off > 0; off >>= 1) {
        s  += __shfl_xor(s, off);
        ss += __shfl_xor(ss, off);
    }
    const float mu  = s * (1.0f / 256.0f);
    const float var = ss * (1.0f / 256.0f) - mu * mu;
    const float rs  = rsqrtf(var + 1e-5f);
    float4 sc = *(const float4*)(scale + lane * 4);
    float4 bi = *(const float4*)(bias + lane * 4);
    float4 o;
    o.x = (v.x - mu) * rs * sc.x + bi.x;
    o.y = (v.y - mu) * rs * sc.y + bi.y;
    o.z = (v.z - mu) * rs * sc.z + bi.z;
    o.w = (v.w - mu) * rs * sc.w + bi.w;
    *(float4*)p = o;
}

// Fused A-generation + Nk contraction, Chebyshev over 4 consecutive s.
// Grid (512 s-tiles, 2 i-halves). Thread t: i = ih*128 + (t&127), j-half = t>>7.
// acc[s=0..3][b=0..7]; partials over j-halves combined via LDS at the end.
__global__ __launch_bounds__(256, 4) void cosnk(const float4* __restrict__ PTK,
                                                const float* __restrict__ xt,
                                                float* __restrict__ out) {
    __shared__ float xs[256][32];   // [j][s*8+b], 32 KB; reused for the reduction
    const int t  = threadIdx.x;
    const int s0 = blockIdx.x * 4;

    {   // stage x_t tile: 32 rows (s,b) x 256 j
        const int slot = t >> 3;        // 0..31 == s*8+b
        const int st   = slot >> 3;
        const int b    = slot & 7;
        const int jb   = (t & 7) * 32;
        const float* src = xt + (size_t)(b * S_ + s0 + st) * 256 + jb;
#pragma unroll
        for (int q = 0; q < 8; ++q) {
            float4 v = *(const float4*)(src + 4 * q);
            xs[jb + 4 * q + 0][slot] = v.x;
            xs[jb + 4 * q + 1][slot] = v.y;
            xs[jb + 4 * q + 2][slot] = v.z;
            xs[jb + 4 * q + 3][slot] = v.w;
        }
    }
    __syncthreads();

    const int i  = blockIdx.y * 128 + (t & 127);
    const int jh = t >> 7;              // 0 or 1
    const int j0 = jh * 128;
    const float sv0 = (float)s0;

    float acc[4][8];
#pragma unroll
    for (int s = 0; s < 4; ++s)
#pragma unroll
        for (int b = 0; b < 8; ++b) acc[s][b] = 0.0f;

    const float4* ptk = PTK + (size_t)(j0 * 6) * 256 + i;

#define CHEB(p_, iT_, k2_)                        \
    do {                                          \
        float f0 = fractf_(sv0 * (iT_));          \
        float c0 = cos2pi(f0);                    \
        float f1 = fractf_(f0 + (iT_));           \
        float c1 = cos2pi(f1);                    \
        float c2 = fmaf((k2_), c1, -c0);          \
        float c3 = fmaf((k2_), c2, -c1);          \
        a0 = fmaf((p_), c0, a0);                  \
        a1 = fmaf((p_), c1, a1);                  \
        a2 = fmaf((p_), c2, a2);                  \
        a3 = fmaf((p_), c3, a3);                  \
    } while (0)

    for (int j = j0; j < j0 + 128; ++j) {
        const float4 q0  = ptk[0];
        const float4 q1  = ptk[256];
        const float4 q2  = ptk[512];
        const float4 q3  = ptk[768];
        const float4 k01 = ptk[1024];
        const float4 k23 = ptk[1280];
        ptk += 1536;

        float a0 = 0.0f, a1 = 0.0f, a2 = 0.0f, a3 = 0.0f;
        CHEB(q0.x, q0.y, k01.x);
        CHEB(q0.z, q0.w, k01.y);
        CHEB(q1.x, q1.y, k01.z);
        CHEB(q1.z, q1.w, k01.w);
        CHEB(q2.x, q2.y, k23.x);
        CHEB(q2.z, q2.w, k23.y);
        CHEB(q3.x, q3.y, k23.z);
        CHEB(q3.z, q3.w, k23.w);

        const float* xrow = &xs[j][0];
        const float as[4] = {a0, a1, a2, a3};
#pragma unroll
        for (int s = 0; s < 4; ++s) {
            const float4 xa = *(const float4*)(xrow + s * 8);
            const float4 xb = *(const float4*)(xrow + s * 8 + 4);
            acc[s][0] = fmaf(as[s], xa.x, acc[s][0]);
            acc[s][1] = fmaf(as[s], xa.y, acc[s][1]);
            acc[s][2] = fmaf(as[s], xa.z, acc[s][2]);
            acc[s][3] = fmaf(as[s], xa.w, acc[s][3]);
            acc[s][4] = fmaf(as[s], xb.x, acc[s][4]);
            acc[s][5] = fmaf(as[s], xb.y, acc[s][5]);
            acc[s][6] = fmaf(as[s], xb.z, acc[s][6]);
            acc[s][7] = fmaf(as[s], xb.w, acc[s][7]);
        }
    }
#undef CHEB

    // combine the two j-half partials, then out += (out already holds residual)
    __syncthreads();
    float* red = &xs[0][0];         // 32*128 floats needed, 8192 available
    const int tl = t & 127;
    if (jh) {
#pragma unroll
        for (int s = 0; s < 4; ++s)
#pragma unroll
            for (int b = 0; b < 8; ++b)
                red[(s * 8 + b) * 128 + tl] = acc[s][b];
    }
    __syncthreads();
    if (!jh) {
#pragma unroll
        for (int s = 0; s < 4; ++s)
#pragma unroll
            for (int b = 0; b < 8; ++b) {
                const float v = acc[s][b] + red[(s * 8 + b) * 128 + tl];
                const size_t o = (size_t)(b * S_ + s0 + s) * 256 + i;
                out[o] += v;
            }
    }
}

extern "C" void kernel_launch(void* const* d_in, const int* in_sizes, int n_in,
                              void* d_out, int out_size, void* d_ws, size_t ws_size,
                              hipStream_t stream) {
    const float* x        = (const float*)d_in[0];
    const float* M        = (const float*)d_in[1];
    const float* P        = (const float*)d_in[2];
    const float* Wres     = (const float*)d_in[3];
    const float* ln_scale = (const float*)d_in[4];
    const float* ln_bias  = (const float*)d_in[5];
    const float* periods  = (const float*)d_in[6];
    // d_in[7] = positions (== arange(S)), used implicitly as s index

    float*  out = (float*)d_out;
    float*  y   = (float*)d_ws;                                      // exactly 16 MiB
    float4* PTK = (float4*)((char*)d_ws + (size_t)16 * 1024 * 1024); // 6 MiB

    prep_ptk<<<256, 256, 0, stream>>>(P, periods, PTK);

    dim3 ggrid(4, 128);
    gemm_kernel<<<ggrid, 256, 0, stream>>>(x, M, Wres, y, out);

    ln_kernel<<<4096, 256, 0, stream>>>(y, ln_scale, ln_bias);

    dim3 cgrid(512, 2);
    cosnk<<<cgrid, 256, 0, stream>>>(PTK, y, out);
}

// Round 3
// 235.459 us; speedup vs baseline: 2.7511x; 1.5078x over previous
//
#include <hip/hip_runtime.h>
#include <hip/hip_bf16.h>
#include <math.h>

#define B_   8
#define S_   2048
#define IN_  512
#define OUT_ 256
#define G_   8

// ws layout (main path):
//   [0, 16MiB)        y   (pre-LN -> x_t in place)   16384*256 f32
//   [16MiB, 32MiB)    Xb  (x as bf16, 16384*512)     -- dead after gemm
//   [16MiB, 22MiB)    PTK (float4 table)             -- aliases Xb, written AFTER gemm
//   [32MiB, 32.5MiB)  Wb  ([M;Wres] as bf16, 512*512)
// fallback path (ws < 32.5MiB): y [0,16MiB), PTK [16MiB,22MiB) -- as R2 (proven fits)

typedef float  f32x4  __attribute__((ext_vector_type(4)));
typedef short  s16x8  __attribute__((ext_vector_type(8)));
typedef __bf16 bf16x8 __attribute__((ext_vector_type(8)));
typedef unsigned short u16x8 __attribute__((ext_vector_type(8)));

__device__ __forceinline__ float cos2pi(float f) {
#if __has_builtin(__builtin_amdgcn_cosf)
    return __builtin_amdgcn_cosf(f);   // v_cos_f32: revolutions (verified R1/R2)
#else
    return __cosf(6.28318530717958647692f * f);
#endif
}

__device__ __forceinline__ float fractf_(float f) {
#if __has_builtin(__builtin_amdgcn_fractf)
    return __builtin_amdgcn_fractf(f);
#else
    return f - floorf(f);
#endif
}

__device__ __forceinline__ unsigned short f2bf(float f) {
    unsigned u = __builtin_bit_cast(unsigned, f);
    u += 0x7fffu + ((u >> 16) & 1u);   // RNE; inputs are finite
    return (unsigned short)(u >> 16);
}

// --- MFMA wrapper: tolerate either V8s(short) or V8y(__bf16) builtin signature ---
template <typename T>
__device__ __forceinline__ auto mfma_bf16_(T a, T b, f32x4 c, int)
    -> decltype(__builtin_amdgcn_mfma_f32_16x16x32_bf16(a, b, c, 0, 0, 0)) {
    return __builtin_amdgcn_mfma_f32_16x16x32_bf16(a, b, c, 0, 0, 0);
}
template <typename T>
__device__ __forceinline__ auto mfma_bf16_(T a, T b, f32x4 c, long)
    -> decltype(__builtin_amdgcn_mfma_f32_16x16x32_bf16(__builtin_bit_cast(bf16x8, a),
                                                        __builtin_bit_cast(bf16x8, b), c, 0, 0, 0)) {
    return __builtin_amdgcn_mfma_f32_16x16x32_bf16(__builtin_bit_cast(bf16x8, a),
                                                   __builtin_bit_cast(bf16x8, b), c, 0, 0, 0);
}
__device__ __forceinline__ f32x4 mfma_bf16(s16x8 a, s16x8 b, f32x4 c) {
    return mfma_bf16_(a, b, c, 0);
}

__device__ __forceinline__ void gld16(const void* g, void* l) {
    __builtin_amdgcn_global_load_lds((const __attribute__((address_space(1))) unsigned int*)g,
                                     (__attribute__((address_space(3))) unsigned int*)l,
                                     16, 0, 0);
}

// ---------------- converts ----------------
__global__ __launch_bounds__(256) void cvt_x(const float* __restrict__ x,
                                             unsigned short* __restrict__ Xb) {
    const int idx = blockIdx.x * 256 + threadIdx.x;   // 1,048,576 threads * 8 elems
    const float4 v0 = *(const float4*)(x + (size_t)idx * 8);
    const float4 v1 = *(const float4*)(x + (size_t)idx * 8 + 4);
    u16x8 o;
    o[0] = f2bf(v0.x); o[1] = f2bf(v0.y); o[2] = f2bf(v0.z); o[3] = f2bf(v0.w);
    o[4] = f2bf(v1.x); o[5] = f2bf(v1.y); o[6] = f2bf(v1.z); o[7] = f2bf(v1.w);
    *(u16x8*)(Xb + (size_t)idx * 8) = o;
}

__global__ __launch_bounds__(256) void cvt_w(const float* __restrict__ M,
                                             const float* __restrict__ Wres,
                                             unsigned short* __restrict__ Wb) {
    const int idx = blockIdx.x * 256 + threadIdx.x;   // 32768 threads
    const int row = idx >> 6;                          // 512 rows
    const int col = (idx & 63) * 8;
    const float* src = (row < 256) ? (M + (size_t)row * 512 + col)
                                   : (Wres + (size_t)(row - 256) * 512 + col);
    const float4 v0 = *(const float4*)(src);
    const float4 v1 = *(const float4*)(src + 4);
    u16x8 o;
    o[0] = f2bf(v0.x); o[1] = f2bf(v0.y); o[2] = f2bf(v0.z); o[3] = f2bf(v0.w);
    o[4] = f2bf(v1.x); o[5] = f2bf(v1.y); o[6] = f2bf(v1.z); o[7] = f2bf(v1.w);
    *(u16x8*)(Wb + (size_t)row * 512 + col) = o;
}

// ---------------- bf16 MFMA GEMM: C[16384,512] = Xb * Wb^T ----------------
// 128x128 tile, BK=64, 4 waves each 64x64. Cols 0..255 -> y, 256..511 -> out.
__global__ __launch_bounds__(256) void gemm_mfma(const unsigned short* __restrict__ Xb,
                                                 const unsigned short* __restrict__ Wb,
                                                 float* __restrict__ y,
                                                 float* __restrict__ out) {
    __shared__ __align__(16) unsigned short At[128 * 64];
    __shared__ __align__(16) unsigned short Bt[128 * 64];
    const int t    = threadIdx.x;
    const int col0 = blockIdx.x * 128;
    const int row0 = blockIdx.y * 128;

    // staging: chunk L (16B) at LDS offset L*16; global chunk XOR-swizzled by row
    const unsigned short* ga[4];
    const unsigned short* gb[4];
    int lofs[4];
#pragma unroll
    for (int cc = 0; cc < 4; ++cc) {
        const int L = cc * 256 + t;
        const int r = L >> 3;
        const int c = (L & 7) ^ (r & 7);
        ga[cc]   = Xb + (size_t)(row0 + r) * 512 + c * 8;
        gb[cc]   = Wb + (size_t)(col0 + r) * 512 + c * 8;
        lofs[cc] = L * 8;
    }

    const int lane = t & 63;
    const int wave = t >> 6;
    const int wm   = (wave & 1) * 64;
    const int wn   = (wave >> 1) * 64;
    const int quad = lane >> 4;
    const int l16  = lane & 15;

    f32x4 acc[4][4];
#pragma unroll
    for (int mi = 0; mi < 4; ++mi)
#pragma unroll
        for (int ni = 0; ni < 4; ++ni) acc[mi][ni] = {0.0f, 0.0f, 0.0f, 0.0f};

    for (int k0 = 0; k0 < 512; k0 += 64) {
        __syncthreads();
#pragma unroll
        for (int cc = 0; cc < 4; ++cc) {
            gld16(ga[cc] + k0, At + lofs[cc]);
            gld16(gb[cc] + k0, Bt + lofs[cc]);
        }
        __syncthreads();   // compiler emits vmcnt(0) drain before s_barrier
#pragma unroll
        for (int ks = 0; ks < 2; ++ks) {
            s16x8 af[4], bf[4];
#pragma unroll
            for (int mi = 0; mi < 4; ++mi) {
                const int cc = (ks * 4 + quad) ^ (l16 & 7);
                const int ra = wm + mi * 16 + l16;
                const int rb = wn + mi * 16 + l16;
                af[mi] = *(const s16x8*)(At + (ra * 8 + cc) * 8);
                bf[mi] = *(const s16x8*)(Bt + (rb * 8 + cc) * 8);
            }
#pragma unroll
            for (int mi = 0; mi < 4; ++mi)
#pragma unroll
                for (int ni = 0; ni < 4; ++ni)
                    acc[mi][ni] = mfma_bf16(af[mi], bf[ni], acc[mi][ni]);
        }
    }

    float* dst   = (col0 < 256) ? y : out;
    const int cb = (col0 & 255) + wn;
#pragma unroll
    for (int mi = 0; mi < 4; ++mi) {
        const int rbase = row0 + wm + mi * 16 + quad * 4;
#pragma unroll
        for (int ni = 0; ni < 4; ++ni) {
            const int col = cb + ni * 16 + l16;
#pragma unroll
            for (int rg = 0; rg < 4; ++rg)
                dst[(size_t)(rbase + rg) * 256 + col] = acc[mi][ni][rg];
        }
    }
}

// ---------------- fallback fp32 GEMM (R2, proven) ----------------
__global__ __launch_bounds__(256) void gemm_kernel(const float* __restrict__ x,
                                                   const float* __restrict__ M,
                                                   const float* __restrict__ Wres,
                                                   float* __restrict__ y,
                                                   float* __restrict__ out) {
    __shared__ float As[8][132];
    __shared__ float Bs[8][132];
    const int ct = blockIdx.x;
    const int rt = blockIdx.y;
    const int t  = threadIdx.x;
    const int row0 = rt * 128;
    const float* W = (ct < 2) ? M : Wres;
    const int wcol0 = (ct & 1) * 128;
    float acc[8][8];
#pragma unroll
    for (int r = 0; r < 8; ++r)
#pragma unroll
        for (int c = 0; c < 8; ++c) acc[r][c] = 0.0f;
    const int lr = t >> 1;
    const int lk = (t & 1) << 2;
    for (int k0 = 0; k0 < 512; k0 += 8) {
        float4 av = *(const float4*)(x + (size_t)(row0 + lr) * 512 + k0 + lk);
        float4 bv = *(const float4*)(W + (size_t)(wcol0 + lr) * 512 + k0 + lk);
        __syncthreads();
        As[lk + 0][lr] = av.x; As[lk + 1][lr] = av.y; As[lk + 2][lr] = av.z; As[lk + 3][lr] = av.w;
        Bs[lk + 0][lr] = bv.x; Bs[lk + 1][lr] = bv.y; Bs[lk + 2][lr] = bv.z; Bs[lk + 3][lr] = bv.w;
        __syncthreads();
        const int tx = t & 15, ty = t >> 4;
#pragma unroll
        for (int kk = 0; kk < 8; ++kk) {
            const float4 a0 = *(const float4*)&As[kk][ty * 8];
            const float4 a1 = *(const float4*)&As[kk][ty * 8 + 4];
            const float4 b0 = *(const float4*)&Bs[kk][tx * 8];
            const float4 b1 = *(const float4*)&Bs[kk][tx * 8 + 4];
            const float ar[8] = {a0.x, a0.y, a0.z, a0.w, a1.x, a1.y, a1.z, a1.w};
            const float br[8] = {b0.x, b0.y, b0.z, b0.w, b1.x, b1.y, b1.z, b1.w};
#pragma unroll
            for (int r = 0; r < 8; ++r)
#pragma unroll
                for (int c = 0; c < 8; ++c) acc[r][c] = fmaf(ar[r], br[c], acc[r][c]);
        }
    }
    const int tx = t & 15, ty = t >> 4;
    float* dst = (ct < 2) ? y : out;
    const int cbase = (ct & 1) * 128 + tx * 8;
#pragma unroll
    for (int r = 0; r < 8; ++r) {
        float4 v0 = {acc[r][0], acc[r][1], acc[r][2], acc[r][3]};
        float4 v1 = {acc[r][4], acc[r][5], acc[r][6], acc[r][7]};
        float* p = dst + (size_t)(row0 + ty * 8 + r) * 256 + cbase;
        *(float4*)(p)     = v0;
        *(float4*)(p + 4) = v1;
    }
}

// ---------------- LayerNorm (in-place) ----------------
__global__ __launch_bounds__(256) void ln_kernel(float* __restrict__ y,
                                                 const float* __restrict__ scale,
                                                 const float* __restrict__ bias) {
    const int t    = threadIdx.x;
    const int row  = blockIdx.x * 4 + (t >> 6);
    const int lane = t & 63;
    float* p = y + (size_t)row * 256 + lane * 4;
    float4 v = *(float4*)p;
    float s  = v.x + v.y + v.z + v.w;
    float ss = v.x * v.x + v.y * v.y + v.z * v.z + v.w * v.w;
#pragma unroll
    for (int off = 32; off > 0; off >>= 1) {
        s  += __shfl_xor(s, off);
        ss += __shfl_xor(ss, off);
    }
    const float mu  = s * (1.0f / 256.0f);
    const float var = ss * (1.0f / 256.0f) - mu * mu;
    const float rs  = rsqrtf(var + 1e-5f);
    float4 sc = *(const float4*)(scale + lane * 4);
    float4 bi = *(const float4*)(bias + lane * 4);
    float4 o;
    o.x = (v.x - mu) * rs * sc.x + bi.x;
    o.y = (v.y - mu) * rs * sc.y + bi.y;
    o.z = (v.z - mu) * rs * sc.z + bi.z;
    o.w = (v.w - mu) * rs * sc.w + bi.w;
    *(float4*)p = o;
}

// ---------------- PTK table: [j][quad0..5][i] float4 ----------------
__global__ __launch_bounds__(256) void prep_ptk(const float* __restrict__ P,
                                                const float* __restrict__ periods,
                                                float4* __restrict__ PTK) {
    const int tid = blockIdx.x * 256 + threadIdx.x;
    const int j = tid >> 8, i = tid & 255;
    float p[8], iT[8], k2[8];
#pragma unroll
    for (int g = 0; g < 8; ++g) {
        const int idx = (i * 256 + j) * 8 + g;
        p[g]  = P[idx];
        iT[g] = 1.0f / periods[idx];
        k2[g] = 2.0f * cos2pi(iT[g]);
    }
    float4* base = PTK + (size_t)(j * 6) * 256 + i;
    base[0]    = make_float4(p[0], iT[0], p[1], iT[1]);
    base[256]  = make_float4(p[2], iT[2], p[3], iT[3]);
    base[512]  = make_float4(p[4], iT[4], p[5], iT[5]);
    base[768]  = make_float4(p[6], iT[6], p[7], iT[7]);
    base[1024] = make_float4(k2[0], k2[1], k2[2], k2[3]);
    base[1280] = make_float4(k2[4], k2[5], k2[6], k2[7]);
}

// ---------------- fused A-gen + contraction, 8 s per block ----------------
// grid 512: XCD-swizzled decode -> ih (i-half) pinned to XCD groups for L2 locality.
__global__ __launch_bounds__(256, 2) void cosnk8(const float4* __restrict__ PTK,
                                                 const float* __restrict__ xt,
                                                 float* __restrict__ out) {
    __shared__ float xs[256][64];   // [j][s*8+b], 64 KB (caps at 2 blocks/CU)
    const int t  = threadIdx.x;
    const int bx = blockIdx.x;
    const int ih = (bx >> 2) & 1;                    // XCDs 0-3 -> ih0, 4-7 -> ih1
    const int stile = ((bx >> 3) << 2) | (bx & 3);   // 0..255
    const int s0 = stile * 8;

    {   // stage x_t: 64 (s,b)-slots x 256 j
        const int slot = t >> 2;        // 0..63 = s*8+b
        const int st   = slot >> 3;
        const int b    = slot & 7;
        const int jb   = (t & 3) * 64;
        const float* src = xt + (size_t)(b * S_ + s0 + st) * 256 + jb;
#pragma unroll
        for (int q = 0; q < 16; ++q) {
            float4 v = *(const float4*)(src + 4 * q);
            xs[jb + 4 * q + 0][slot] = v.x;
            xs[jb + 4 * q + 1][slot] = v.y;
            xs[jb + 4 * q + 2][slot] = v.z;
            xs[jb + 4 * q + 3][slot] = v.w;
        }
    }
    __syncthreads();

    const int i  = ih * 128 + (t & 127);
    const int jh = t >> 7;
    const int j0 = jh * 128;
    const float sv0 = (float)s0;

    float acc[8][8];
#pragma unroll
    for (int s = 0; s < 8; ++s)
#pragma unroll
        for (int b = 0; b < 8; ++b) acc[s][b] = 0.0f;

    const float4* ptk = PTK + (size_t)(j0 * 6) * 256 + i;
    float4 q0 = ptk[0],    q1 = ptk[256],  q2 = ptk[512];
    float4 q3 = ptk[768], k01 = ptk[1024], k23 = ptk[1280];

#define CHEB8(p_, iT_, k2_)                         \
    do {                                            \
        float f0 = fractf_(sv0 * (iT_));            \
        float c0 = cos2pi(f0);                      \
        float c1 = cos2pi(fractf_(f0 + (iT_)));     \
        float c2 = fmaf((k2_), c1, -c0);            \
        float c3 = fmaf((k2_), c2, -c1);            \
        float c4 = fmaf((k2_), c3, -c2);            \
        float c5 = fmaf((k2_), c4, -c3);            \
        float c6 = fmaf((k2_), c5, -c4);            \
        float c7 = fmaf((k2_), c6, -c5);            \
        a0 = fmaf((p_), c0, a0); a1 = fmaf((p_), c1, a1); \
        a2 = fmaf((p_), c2, a2); a3 = fmaf((p_), c3, a3); \
        a4 = fmaf((p_), c4, a4); a5 = fmaf((p_), c5, a5); \
        a6 = fmaf((p_), c6, a6); a7 = fmaf((p_), c7, a7); \
    } while (0)

    for (int jj = 0; jj < 128; ++jj) {
        // prefetch next j's 6 vectors (clamped on last iter; hides L2 latency)
        const float4* pn = ptk + ((jj < 127) ? 1536 : 0);
        const float4 n0 = pn[0],   n1 = pn[256],  n2 = pn[512];
        const float4 n3 = pn[768], n4 = pn[1024], n5 = pn[1280];

        float a0 = 0.f, a1 = 0.f, a2 = 0.f, a3 = 0.f, a4 = 0.f, a5 = 0.f, a6 = 0.f, a7 = 0.f;
        CHEB8(q0.x, q0.y, k01.x);
        CHEB8(q0.z, q0.w, k01.y);
        CHEB8(q1.x, q1.y, k01.z);
        CHEB8(q1.z, q1.w, k01.w);
        CHEB8(q2.x, q2.y, k23.x);
        CHEB8(q2.z, q2.w, k23.y);
        CHEB8(q3.x, q3.y, k23.z);
        CHEB8(q3.z, q3.w, k23.w);

        const float* xrow = &xs[j0 + jj][0];
        const float as_[8] = {a0, a1, a2, a3, a4, a5, a6, a7};
#pragma unroll
        for (int s = 0; s < 8; ++s) {
            const float4 xa = *(const float4*)(xrow + s * 8);
            const float4 xb = *(const float4*)(xrow + s * 8 + 4);
            acc[s][0] = fmaf(as_[s], xa.x, acc[s][0]);
            acc[s][1] = fmaf(as_[s], xa.y, acc[s][1]);
            acc[s][2] = fmaf(as_[s], xa.z, acc[s][2]);
            acc[s][3] = fmaf(as_[s], xa.w, acc[s][3]);
            acc[s][4] = fmaf(as_[s], xb.x, acc[s][4]);
            acc[s][5] = fmaf(as_[s], xb.y, acc[s][5]);
            acc[s][6] = fmaf(as_[s], xb.z, acc[s][6]);
            acc[s][7] = fmaf(as_[s], xb.w, acc[s][7]);
        }
        q0 = n0; q1 = n1; q2 = n2; q3 = n3; k01 = n4; k23 = n5;
        ptk = pn;
    }
#undef CHEB8

    // combine j-half partials; out += (out holds residual from gemm)
    __syncthreads();
    float* red = &xs[0][0];         // need 64*128 = 32 KB of the 64 KB
    const int tl = t & 127;
    if (jh) {
#pragma unroll
        for (int slot = 0; slot < 64; ++slot)
            red[slot * 128 + tl] = acc[slot >> 3][slot & 7];
    }
    __syncthreads();
    if (!jh) {
#pragma unroll
        for (int slot = 0; slot < 64; ++slot) {
            const int st = slot >> 3, b = slot & 7;
            const float v = acc[st][b] + red[slot * 128 + tl];
            out[(size_t)(b * S_ + s0 + st) * 256 + i] += v;
        }
    }
}

extern "C" void kernel_launch(void* const* d_in, const int* in_sizes, int n_in,
                              void* d_out, int out_size, void* d_ws, size_t ws_size,
                              hipStream_t stream) {
    const float* x        = (const float*)d_in[0];
    const float* M        = (const float*)d_in[1];
    const float* P        = (const float*)d_in[2];
    const float* Wres     = (const float*)d_in[3];
    const float* ln_scale = (const float*)d_in[4];
    const float* ln_bias  = (const float*)d_in[5];
    const float* periods  = (const float*)d_in[6];

    float* out = (float*)d_out;
    char*  wsb = (char*)d_ws;
    float* y   = (float*)wsb;                                       // 16 MiB
    unsigned short* Xb = (unsigned short*)(wsb + (size_t)16 * 1024 * 1024); // 16 MiB
    float4* PTK        = (float4*)(wsb + (size_t)16 * 1024 * 1024);        // aliases Xb
    unsigned short* Wb = (unsigned short*)(wsb + (size_t)32 * 1024 * 1024); // 0.5 MiB

    const bool use_mfma = (ws_size >= (size_t)34078720);  // 32.5 MiB needed

    if (use_mfma) {
        cvt_x<<<4096, 256, 0, stream>>>(x, Xb);
        cvt_w<<<128, 256, 0, stream>>>(M, Wres, Wb);
        dim3 ggrid(4, 128);
        gemm_mfma<<<ggrid, 256, 0, stream>>>(Xb, Wb, y, out);
    } else {
        dim3 ggrid(4, 128);
        gemm_kernel<<<ggrid, 256, 0, stream>>>(x, M, Wres, y, out);
    }

    ln_kernel<<<4096, 256, 0, stream>>>(y, ln_scale, ln_bias);

    prep_ptk<<<256, 256, 0, stream>>>(P, periods, PTK);  // after gemm (PTK aliases Xb)

    cosnk8<<<512, 256, 0, stream>>>(PTK, y, out);
}